// Round 2
// baseline (25590.312 us; speedup 1.0000x reference)
//
#include <hip/hip_runtime.h>
#include <hip/hip_bf16.h>

typedef __attribute__((ext_vector_type(8))) short bf16x8;
typedef __attribute__((ext_vector_type(4))) float f32x4;
typedef unsigned int u32;

#define D0 8
#define D1 8

__device__ __forceinline__ short f2bf(float f) {
  __hip_bfloat16 h = __float2bfloat16(f);
  return *reinterpret_cast<short*>(&h);
}
__device__ __forceinline__ float bf2f(short s) {
  __hip_bfloat16 h;
  *reinterpret_cast<short*>(&h) = s;
  return __bfloat162float(h);
}
__device__ __forceinline__ float sigm(float x) { return 1.f / (1.f + __expf(-x)); }

// ---------------- precompute kernels ----------------
// dst[nf][ks][lane][8] = bf16(src[(nf*16+(lane&15))*row_stride + col_off + ks*32 + (lane>>4)*8 + e])
__global__ void swz_generic(const float* __restrict__ src, short* __restrict__ dst,
                            int row_stride, int col_off, int nks, int nunits) {
  int uid = blockIdx.x * blockDim.x + threadIdx.x;
  if (uid >= nunits) return;
  int lane = uid & 63;
  int rem  = uid >> 6;
  int ks = rem % nks;
  int nf = rem / nks;
  int row = nf * 16 + (lane & 15);
  int k0  = col_off + ks * 32 + (lane >> 4) * 8;
  const float* s = src + (size_t)row * row_stride + k0;
  short v[8];
#pragma unroll
  for (int e = 0; e < 8; ++e) v[e] = f2bf(s[e]);
  *reinterpret_cast<int4*>(dst + (size_t)uid * 8) = *reinterpret_cast<int4*>(v);
}

__global__ void xpose_kernel(const int* __restrict__ x, int* __restrict__ xT) {
  int i = blockIdx.x * blockDim.x + threadIdx.x;   // 131072
  int b = i >> 10, t = i & 1023;
  xT[t * 128 + b] = x[i];
}

// table[v][n] = sum_k emb[v][k]*W0[n][k] + b0[n]   (M=256,N=2048,K=512 bf16 MFMA)
__global__ __launch_bounds__(512) void table_kernel(
    const float* __restrict__ emb, const short* __restrict__ Wx,
    const float* __restrict__ b0, float* __restrict__ table) {
  __shared__ __align__(16) char smem[65536];
  const int tid = threadIdx.x;
  const int m0 = blockIdx.x * 64;
  const int nt = blockIdx.y;
  for (int i = tid; i < 4096; i += 512) {
    int row = i >> 6, seg = i & 63;
    const float* sp = emb + (size_t)(m0 + row) * 512 + seg * 8;
    short v[8];
#pragma unroll
    for (int e = 0; e < 8; ++e) v[e] = f2bf(sp[e]);
    *reinterpret_cast<int4*>(smem + row * 1024 + ((seg * 16) ^ ((row & 7) << 4))) =
        *reinterpret_cast<int4*>(v);
  }
  __syncthreads();
  const int w = tid >> 6, lane = tid & 63, l15 = lane & 15, lq = lane >> 4;
  const int mg = (w >> 2) * 32, np = w & 3;
  const char* ap = smem + (mg + l15) * 1024;
  const int swz = (l15 & 7) << 4;
  const int nfbase = nt * 8 + np * 2;
  const short* bp0 = Wx + (size_t)nfbase * 8192 + lane * 8;
  const short* bp1 = bp0 + 8192;
  f32x4 acc[2][2] = {};
#pragma unroll 4
  for (int ks = 0; ks < 16; ++ks) {
    int kb = ks * 64 + lq * 16;
    bf16x8 a0 = *reinterpret_cast<const bf16x8*>(ap + (kb ^ swz));
    bf16x8 a1 = *reinterpret_cast<const bf16x8*>(ap + 16 * 1024 + (kb ^ swz));
    bf16x8 bv0 = *reinterpret_cast<const bf16x8*>(bp0 + ks * 512);
    bf16x8 bv1 = *reinterpret_cast<const bf16x8*>(bp1 + ks * 512);
    acc[0][0] = __builtin_amdgcn_mfma_f32_16x16x32_bf16(a0, bv0, acc[0][0], 0, 0, 0);
    acc[1][0] = __builtin_amdgcn_mfma_f32_16x16x32_bf16(a1, bv0, acc[1][0], 0, 0, 0);
    acc[0][1] = __builtin_amdgcn_mfma_f32_16x16x32_bf16(a0, bv1, acc[0][1], 0, 0, 0);
    acc[1][1] = __builtin_amdgcn_mfma_f32_16x16x32_bf16(a1, bv1, acc[1][1], 0, 0, 0);
  }
#pragma unroll
  for (int mf = 0; mf < 2; ++mf)
#pragma unroll
    for (int nfi = 0; nfi < 2; ++nfi)
#pragma unroll
      for (int r = 0; r < 4; ++r) {
        int ncol = nt * 128 + np * 32 + nfi * 16 + l15;
        int vrow = m0 + mg + mf * 16 + lq * 4 + r;
        table[(size_t)vrow * 2048 + ncol] = acc[mf][nfi][r] + b0[ncol];
      }
}

// ---------------- persistent kernel: sync helpers ----------------
__device__ __forceinline__ void wg_wait(u32* p, u32 target, int tid) {
  if (tid == 0) {
    while (__hip_atomic_load(p, __ATOMIC_RELAXED, __HIP_MEMORY_SCOPE_AGENT) < target)
      __builtin_amdgcn_s_sleep(2);
    (void)__hip_atomic_fetch_add(p, 0u, __ATOMIC_ACQUIRE, __HIP_MEMORY_SCOPE_AGENT);
  }
  __syncthreads();
}
__device__ __forceinline__ void sig_done(u32* p, int tid) {
  // call immediately after a __syncthreads() that ends the reads of the slot
  if (tid == 0) (void)__hip_atomic_fetch_add(p, 1u, __ATOMIC_RELEASE, __HIP_MEMORY_SCOPE_AGENT);
}
__device__ __forceinline__ void sig_ready(u32* p, int tid) {
  __threadfence();
  __syncthreads();
  if (tid == 0) (void)__hip_atomic_fetch_add(p, 1u, __ATOMIC_RELEASE, __HIP_MEMORY_SCOPE_AGENT);
}

// ---------------- LSTM layer role ----------------
template<int L>
__device__ void lstm_role(char* smem, int rid, int tid,
    const short* __restrict__ Wsw, const float* __restrict__ table,
    const float* __restrict__ bias1, const int* __restrict__ xT,
    short* __restrict__ h0ring, short* __restrict__ h1ring,
    const short* __restrict__ zslot, u32* __restrict__ flags)
{
  u32* ready0 = flags;
  u32* done0  = flags + 2048;
  u32* ready1 = flags + 4096;
  u32* done1  = flags + 6144;
  const int mh = rid & 1, cg = rid >> 1;
  const int m0 = mh * 64, cbase = cg * 32;
  const int w = tid >> 6, lane = tid & 63;
  const int g = w & 3, mg = (w >> 2) * 32;
  const int l15 = lane & 15, lq = lane >> 4;
  const int swz = (l15 & 7) << 4;
  const int ROWB = (L == 0) ? 1024 : 2048;   // staged row bytes
  const int NKS  = (L == 0) ? 16 : 32;
  const int nfbase = g * 32 + cg * 2;
  const short* bbase = Wsw + (size_t)nfbase * (NKS * 512) + lane * 8;
  int* xidsl = reinterpret_cast<int*>(smem + 131072);
  float creg[4] = {0.f, 0.f, 0.f, 0.f};
  float breg[4][4];
  if (L == 1) {
#pragma unroll
    for (int k = 0; k < 4; ++k) {
      int col = (tid + k * 512) & 31;
#pragma unroll
      for (int gg = 0; gg < 4; ++gg) breg[gg][k] = bias1[gg * 512 + cbase + col];
    }
  }
  u32* myready = (L == 0) ? ready0 : ready1;

  for (int t = 0; t < 1024; ++t) {
    if (L == 0) {
      if (t >= D0) wg_wait(&done0[mh * 1024 + t - D0], 32u, tid);
      if (t >= 1)  wg_wait(&ready0[mh * 1024 + t - 1], 16u, tid);
    } else {
      if (t >= D1) wg_wait(&done1[mh * 1024 + t - D1], 18u, tid);
      wg_wait(&ready0[mh * 1024 + t], 16u, tid);
      if (t >= 1) wg_wait(&ready1[mh * 1024 + t - 1], 16u, tid);
    }
    // ---- stage z into LDS (XOR-swizzled) ----
    if (L == 0) {
      if (tid < 64) xidsl[tid] = xT[t * 128 + m0 + tid];
      const short* hsrc = t ? h0ring + (size_t)((t - 1) & 7) * 65536 : zslot;
      for (int i = tid; i < 4096; i += 512) {
        int row = i >> 6, seg = i & 63;
        int4 v = *reinterpret_cast<const int4*>(hsrc + (size_t)(m0 + row) * 512 + seg * 8);
        *reinterpret_cast<int4*>(smem + row * 1024 + ((seg * 16) ^ ((row & 7) << 4))) = v;
      }
      __syncthreads();
      if (t >= 1) sig_done(&done0[mh * 1024 + t - 1], tid);
    } else {
      const short* s0 = h0ring + (size_t)(t & 7) * 65536;
      const short* s1 = t ? h1ring + (size_t)((t - 1) & 7) * 65536 : zslot;
      for (int i = tid; i < 8192; i += 512) {
        int row = i >> 7, seg = i & 127;
        const short* src = (seg < 64) ? s0 + (size_t)(m0 + row) * 512 + seg * 8
                                      : s1 + (size_t)(m0 + row) * 512 + (seg - 64) * 8;
        int4 v = *reinterpret_cast<const int4*>(src);
        *reinterpret_cast<int4*>(smem + row * 2048 + ((seg * 16) ^ ((row & 7) << 4))) = v;
      }
      __syncthreads();
      sig_done(&done0[mh * 1024 + t], tid);
      if (t >= 1) sig_done(&done1[mh * 1024 + t - 1], tid);
    }
    // ---- MFMA: [64 rows] x [128 gate-cols], K = NKS*32 ----
    f32x4 acc[2][2] = {};
    const char* ap = smem + (size_t)(mg + l15) * ROWB;
#pragma unroll 4
    for (int ks = 0; ks < NKS; ++ks) {
      int kb = ks * 64 + lq * 16;
      bf16x8 a0 = *reinterpret_cast<const bf16x8*>(ap + (kb ^ swz));
      bf16x8 a1 = *reinterpret_cast<const bf16x8*>(ap + 16 * ROWB + (kb ^ swz));
      bf16x8 b0 = *reinterpret_cast<const bf16x8*>(bbase + ks * 512);
      bf16x8 b1 = *reinterpret_cast<const bf16x8*>(bbase + NKS * 512 + ks * 512);
      acc[0][0] = __builtin_amdgcn_mfma_f32_16x16x32_bf16(a0, b0, acc[0][0], 0, 0, 0);
      acc[1][0] = __builtin_amdgcn_mfma_f32_16x16x32_bf16(a1, b0, acc[1][0], 0, 0, 0);
      acc[0][1] = __builtin_amdgcn_mfma_f32_16x16x32_bf16(a0, b1, acc[0][1], 0, 0, 0);
      acc[1][1] = __builtin_amdgcn_mfma_f32_16x16x32_bf16(a1, b1, acc[1][1], 0, 0, 0);
    }
    __syncthreads();
    float* gl = reinterpret_cast<float*>(smem);   // [4][64][32] f32, aliases staging
#pragma unroll
    for (int mf = 0; mf < 2; ++mf)
#pragma unroll
      for (int nfi = 0; nfi < 2; ++nfi)
#pragma unroll
        for (int r = 0; r < 4; ++r)
          gl[(g * 64 + mg + mf * 16 + lq * 4 + r) * 32 + nfi * 16 + l15] = acc[mf][nfi][r];
    __syncthreads();
    // ---- elementwise; c lives in registers (fixed (row,col) per thread) ----
    short* hdst = ((L == 0) ? h0ring : h1ring) + (size_t)(t & 7) * 65536;
#pragma unroll
    for (int k = 0; k < 4; ++k) {
      int i = tid + k * 512;
      int col = i & 31, row = i >> 5;
      float gi, gf, go, gG;
      if (L == 0) {
        const float* tb = table + (size_t)xidsl[row] * 2048 + cbase + col;
        gi = gl[(0 * 64 + row) * 32 + col] + tb[0];
        gf = gl[(1 * 64 + row) * 32 + col] + tb[512];
        go = gl[(2 * 64 + row) * 32 + col] + tb[1024];
        gG = gl[(3 * 64 + row) * 32 + col] + tb[1536];
      } else {
        gi = gl[(0 * 64 + row) * 32 + col] + breg[0][k];
        gf = gl[(1 * 64 + row) * 32 + col] + breg[1][k];
        go = gl[(2 * 64 + row) * 32 + col] + breg[2][k];
        gG = gl[(3 * 64 + row) * 32 + col] + breg[3][k];
      }
      float cv = sigm(gf) * creg[k] + sigm(gi) * tanhf(gG);
      creg[k] = cv;
      hdst[(size_t)(m0 + row) * 512 + cbase + col] = f2bf(sigm(go) * tanhf(cv));
    }
    sig_ready(&myready[mh * 1024 + t], tid);
  }
}

// ---------------- projection role (LN + [32x256] K=512 GEMM) ----------------
__device__ void proj_role(char* smem, int pid, int tid,
    const short* __restrict__ h1ring, u32* __restrict__ flags,
    const short* __restrict__ pWswz, const float* __restrict__ lng,
    const float* __restrict__ lnb, const float* __restrict__ pb,
    float* __restrict__ out)
{
  u32* ready1 = flags + 4096;
  u32* done1  = flags + 6144;
  const int mh = pid >> 1;
  const int prow0 = pid * 32;
  const int w = tid >> 6, lane = tid & 63, l15 = lane & 15, lq = lane >> 4;
  const int swz = (l15 & 7) << 4;
  const short* bp0 = pWswz + (size_t)(w * 2) * 8192 + lane * 8;
  const short* bp1 = bp0 + 8192;

  for (int t = 0; t < 1024; ++t) {
    wg_wait(&ready1[mh * 1024 + t], 16u, tid);
    const short* h1p = h1ring + (size_t)(t & 7) * 65536;
    for (int i = tid; i < 2048; i += 512) {
      int row = i >> 6, seg = i & 63;
      *reinterpret_cast<int4*>(smem + row * 1024 + seg * 16) =
          *reinterpret_cast<const int4*>(h1p + (size_t)(prow0 + row) * 512 + seg * 8);
    }
    __syncthreads();
    sig_done(&done1[mh * 1024 + t], tid);
    {
      int row = tid >> 4, j = tid & 15;
      const short* hr = reinterpret_cast<const short*>(smem) + row * 512;
      float s1 = 0.f, s2 = 0.f;
#pragma unroll
      for (int kk = 0; kk < 32; ++kk) {
        float v = bf2f(hr[j * 32 + kk]);
        s1 += v; s2 += v * v;
      }
#pragma unroll
      for (int d = 1; d < 16; d <<= 1) { s1 += __shfl_xor(s1, d, 64); s2 += __shfl_xor(s2, d, 64); }
      float mu = s1 * (1.f / 512.f);
      float rs = rsqrtf(s2 * (1.f / 512.f) - mu * mu + 1e-5f);
      char* zn = smem + 32768;
#pragma unroll
      for (int kk = 0; kk < 32; ++kk) {
        int k = j * 32 + kk;
        float v = bf2f(hr[k]);
        float nv = (v - mu) * rs * lng[k] + lnb[k];
        *reinterpret_cast<short*>(zn + row * 1024 + ((k * 2) ^ ((row & 7) << 4))) = f2bf(nv);
      }
    }
    __syncthreads();
    const char* ap = smem + 32768 + l15 * 1024;
    f32x4 acc[2][2] = {};
#pragma unroll 4
    for (int ks = 0; ks < 16; ++ks) {
      int kb = ks * 64 + lq * 16;
      bf16x8 a0 = *reinterpret_cast<const bf16x8*>(ap + (kb ^ swz));
      bf16x8 a1 = *reinterpret_cast<const bf16x8*>(ap + 16 * 1024 + (kb ^ swz));
      bf16x8 bv0 = *reinterpret_cast<const bf16x8*>(bp0 + ks * 512);
      bf16x8 bv1 = *reinterpret_cast<const bf16x8*>(bp1 + ks * 512);
      acc[0][0] = __builtin_amdgcn_mfma_f32_16x16x32_bf16(a0, bv0, acc[0][0], 0, 0, 0);
      acc[1][0] = __builtin_amdgcn_mfma_f32_16x16x32_bf16(a1, bv0, acc[1][0], 0, 0, 0);
      acc[0][1] = __builtin_amdgcn_mfma_f32_16x16x32_bf16(a0, bv1, acc[0][1], 0, 0, 0);
      acc[1][1] = __builtin_amdgcn_mfma_f32_16x16x32_bf16(a1, bv1, acc[1][1], 0, 0, 0);
    }
#pragma unroll
    for (int mf = 0; mf < 2; ++mf)
#pragma unroll
      for (int nfi = 0; nfi < 2; ++nfi)
#pragma unroll
        for (int r = 0; r < 4; ++r) {
          int vcol = (w * 2 + nfi) * 16 + l15;
          int rowg = prow0 + mf * 16 + lq * 4 + r;
          out[(size_t)rowg * 262144 + (size_t)t * 256 + vcol] = acc[mf][nfi][r] + pb[vcol];
        }
  }
}

__global__ __launch_bounds__(512) void persist_kernel(
    const short* __restrict__ W0h, const short* __restrict__ W1,
    const float* __restrict__ table, const float* __restrict__ bias1,
    const int* __restrict__ xT, short* __restrict__ h0ring, short* __restrict__ h1ring,
    const short* __restrict__ zslot, u32* __restrict__ flags,
    const short* __restrict__ pWswz, const float* __restrict__ lng,
    const float* __restrict__ lnb, const float* __restrict__ pb, float* __restrict__ out)
{
  __shared__ __align__(16) char smem[131328];
  const int wg = blockIdx.x, tid = threadIdx.x;
  if (wg < 32)
    lstm_role<0>(smem, wg, tid, W0h, table, nullptr, xT, h0ring, h1ring, zslot, flags);
  else if (wg < 64)
    lstm_role<1>(smem, wg - 32, tid, W1, nullptr, bias1, xT, h0ring, h1ring, zslot, flags);
  else
    proj_role(smem, wg - 64, tid, h1ring, flags, pWswz, lng, lnb, pb, out);
}

extern "C" void kernel_launch(void* const* d_in, const int* in_sizes, int n_in,
                              void* d_out, int out_size, void* d_ws, size_t ws_size,
                              hipStream_t stream) {
  const int*   x    = (const int*)d_in[0];
  const float* emb  = (const float*)d_in[1];
  const float* W    = (const float*)d_in[2];
  const float* bias = (const float*)d_in[3];
  const float* lng  = (const float*)d_in[4];
  const float* lnb  = (const float*)d_in[5];
  const float* pW   = (const float*)d_in[6];
  const float* pb   = (const float*)d_in[7];
  float* out = (float*)d_out;

  char* ws = (char*)d_ws;
  short* W0h   = (short*)(ws + 0);          // 2 MB: layer0 h-part swizzled (K=512)
  short* W1sw  = (short*)(ws + 2097152);    // 4 MB: layer1 full (K=1024)
  short* W0x   = (short*)(ws + 6291456);    // 2 MB: layer0 x-part (table build)
  short* pWsw  = (short*)(ws + 8388608);    // 256 KB
  float* table = (float*)(ws + 8650752);    // 2 MB: [256][2048] gates_x + b0
  int*   xT    = (int*)(ws + 10747904);     // 512 KB: [1024][128]
  short* h0ring= (short*)(ws + 11272192);   // 1 MB: 8 x [128][512] bf16
  short* h1ring= (short*)(ws + 12320768);   // 1 MB
  short* zslot = (short*)(ws + 13369344);   // 128 KB zeros (t=0 h_prev)
  u32*   flags = (u32*)(ws + 13500416);     // 32 KB counters

  hipMemsetAsync(ws + 13369344, 0, 131072 + 32768, stream);   // zslot + flags
  swz_generic<<<dim3(512), dim3(256), 0, stream>>>(W, W0h, 1024, 512, 16, 131072);
  swz_generic<<<dim3(1024), dim3(256), 0, stream>>>(W + 2048 * 1024, W1sw, 1024, 0, 32, 262144);
  swz_generic<<<dim3(512), dim3(256), 0, stream>>>(W, W0x, 1024, 0, 16, 131072);
  swz_generic<<<dim3(64), dim3(256), 0, stream>>>(pW, pWsw, 512, 0, 16, 16384);
  xpose_kernel<<<dim3(512), dim3(256), 0, stream>>>(x, xT);
  table_kernel<<<dim3(4, 16), dim3(512), 0, stream>>>(emb, W0x, bias, table);

  persist_kernel<<<dim3(68), dim3(512), 0, stream>>>(
      W0h, W1sw, table, bias + 2048, xT, h0ring, h1ring, zslot, flags,
      pWsw, lng, lnb, pb, out);
}

// Round 3
// 12433.821 us; speedup vs baseline: 2.0581x; 2.0581x over previous
//
#include <hip/hip_runtime.h>
#include <hip/hip_bf16.h>

typedef __attribute__((ext_vector_type(8))) short bf16x8;
typedef __attribute__((ext_vector_type(4))) float f32x4;
typedef unsigned int u32;
typedef unsigned long long u64;

__device__ __forceinline__ short f2bf(float f) {
  __hip_bfloat16 h = __float2bfloat16(f);
  return *reinterpret_cast<short*>(&h);
}
__device__ __forceinline__ float bf2f(short s) {
  __hip_bfloat16 h;
  *reinterpret_cast<short*>(&h) = s;
  return __bfloat162float(h);
}
__device__ __forceinline__ float sigm(float x) { return 1.f / (1.f + __expf(-x)); }

// ---- relaxed agent-scope primitives: no wbl2/inv, served at MALL ----
__device__ __forceinline__ u32 ld_flag(const u32* p) {
  return __hip_atomic_load(const_cast<u32*>(p), __ATOMIC_RELAXED, __HIP_MEMORY_SCOPE_AGENT);
}
__device__ __forceinline__ void add_flag(u32* p) {
  (void)__hip_atomic_fetch_add(p, 1u, __ATOMIC_RELAXED, __HIP_MEMORY_SCOPE_AGENT);
}
__device__ __forceinline__ u64 ld_h8(const u64* p) {
  return __hip_atomic_load(const_cast<u64*>(p), __ATOMIC_RELAXED, __HIP_MEMORY_SCOPE_AGENT);
}
__device__ __forceinline__ void st_h8(u64* p, u64 v) {
  __hip_atomic_store(p, v, __ATOMIC_RELAXED, __HIP_MEMORY_SCOPE_AGENT);
}
__device__ __forceinline__ void vm_drain() { asm volatile("s_waitcnt vmcnt(0)" ::: "memory"); }

__device__ __forceinline__ void wait3(const u32* p1, u32 t1, const u32* p2, u32 t2,
                                      const u32* p3, u32 t3) {
  for (;;) {
    bool ok = true;
    u32 a = p1 ? ld_flag(p1) : 0xffffffffu;
    u32 b = p2 ? ld_flag(p2) : 0xffffffffu;
    u32 c = p3 ? ld_flag(p3) : 0xffffffffu;
    if (p1 && a < t1) ok = false;
    if (p2 && b < t2) ok = false;
    if (p3 && c < t3) ok = false;
    if (ok) return;
    __builtin_amdgcn_s_sleep(1);
  }
}

// ---------------- precompute kernels ----------------
__global__ void swz_generic(const float* __restrict__ src, short* __restrict__ dst,
                            int row_stride, int col_off, int nks, int nunits) {
  int uid = blockIdx.x * blockDim.x + threadIdx.x;
  if (uid >= nunits) return;
  int lane = uid & 63;
  int rem  = uid >> 6;
  int ks = rem % nks;
  int nf = rem / nks;
  int row = nf * 16 + (lane & 15);
  int k0  = col_off + ks * 32 + (lane >> 4) * 8;
  const float* s = src + (size_t)row * row_stride + k0;
  short v[8];
#pragma unroll
  for (int e = 0; e < 8; ++e) v[e] = f2bf(s[e]);
  *reinterpret_cast<int4*>(dst + (size_t)uid * 8) = *reinterpret_cast<int4*>(v);
}

__global__ void xpose_kernel(const int* __restrict__ x, int* __restrict__ xT) {
  int i = blockIdx.x * blockDim.x + threadIdx.x;   // 131072
  int b = i >> 10, t = i & 1023;
  xT[t * 128 + b] = x[i];
}

__global__ __launch_bounds__(512) void table_kernel(
    const float* __restrict__ emb, const short* __restrict__ Wx,
    const float* __restrict__ b0, float* __restrict__ table) {
  __shared__ __align__(16) char smem[65536];
  const int tid = threadIdx.x;
  const int m0 = blockIdx.x * 64;
  const int nt = blockIdx.y;
  for (int i = tid; i < 4096; i += 512) {
    int row = i >> 6, seg = i & 63;
    const float* sp = emb + (size_t)(m0 + row) * 512 + seg * 8;
    short v[8];
#pragma unroll
    for (int e = 0; e < 8; ++e) v[e] = f2bf(sp[e]);
    *reinterpret_cast<int4*>(smem + row * 1024 + ((seg * 16) ^ ((row & 7) << 4))) =
        *reinterpret_cast<int4*>(v);
  }
  __syncthreads();
  const int w = tid >> 6, lane = tid & 63, l15 = lane & 15, lq = lane >> 4;
  const int mg = (w >> 2) * 32, np = w & 3;
  const char* ap = smem + (mg + l15) * 1024;
  const int swz = (l15 & 7) << 4;
  const int nfbase = nt * 8 + np * 2;
  const short* bp0 = Wx + (size_t)nfbase * 8192 + lane * 8;
  const short* bp1 = bp0 + 8192;
  f32x4 acc[2][2] = {};
#pragma unroll 4
  for (int ks = 0; ks < 16; ++ks) {
    int kb = ks * 64 + lq * 16;
    bf16x8 a0 = *reinterpret_cast<const bf16x8*>(ap + (kb ^ swz));
    bf16x8 a1 = *reinterpret_cast<const bf16x8*>(ap + 16 * 1024 + (kb ^ swz));
    bf16x8 bv0 = *reinterpret_cast<const bf16x8*>(bp0 + ks * 512);
    bf16x8 bv1 = *reinterpret_cast<const bf16x8*>(bp1 + ks * 512);
    acc[0][0] = __builtin_amdgcn_mfma_f32_16x16x32_bf16(a0, bv0, acc[0][0], 0, 0, 0);
    acc[1][0] = __builtin_amdgcn_mfma_f32_16x16x32_bf16(a1, bv0, acc[1][0], 0, 0, 0);
    acc[0][1] = __builtin_amdgcn_mfma_f32_16x16x32_bf16(a0, bv1, acc[0][1], 0, 0, 0);
    acc[1][1] = __builtin_amdgcn_mfma_f32_16x16x32_bf16(a1, bv1, acc[1][1], 0, 0, 0);
  }
#pragma unroll
  for (int mf = 0; mf < 2; ++mf)
#pragma unroll
    for (int nfi = 0; nfi < 2; ++nfi)
#pragma unroll
      for (int r = 0; r < 4; ++r) {
        int ncol = nt * 128 + np * 32 + nfi * 16 + l15;
        int vrow = m0 + mg + mf * 16 + lq * 4 + r;
        table[(size_t)vrow * 2048 + ncol] = acc[mf][nfi][r] + b0[ncol];
      }
}

// ---------------- LSTM layer role ----------------
template<int L>
__device__ void lstm_role(char* smem, int rid, int tid,
    const short* __restrict__ Wsw, const float* __restrict__ table,
    const float* __restrict__ bias1, const int* __restrict__ xT,
    short* __restrict__ h0ring, short* __restrict__ h1ring,
    const short* __restrict__ zslot, u32* __restrict__ flags)
{
  u32* ready0 = flags;
  u32* done0  = flags + 2048;
  u32* ready1 = flags + 4096;
  u32* done1  = flags + 6144;
  const int mh = rid & 1, cg = rid >> 1;
  const int m0 = mh * 64, cbase = cg * 32;
  const int w = tid >> 6, lane = tid & 63;
  const int g = w & 3, mg = (w >> 2) * 32;
  const int l15 = lane & 15, lq = lane >> 4;
  const int swz = (l15 & 7) << 4;
  const int ROWB = (L == 0) ? 1024 : 2048;
  const int NKS  = (L == 0) ? 16 : 32;
  const int nfbase = g * 32 + cg * 2;
  const short* bbase = Wsw + (size_t)nfbase * (NKS * 512) + lane * 8;
  int* xidsl = reinterpret_cast<int*>(smem + 131072);
  // elementwise ownership: row_e = tid>>3 (0..63), colq = (tid&7)*4 (4 consecutive cols)
  const int row_e = tid >> 3, colq = (tid & 7) * 4;
  const int esw = (row_e & 7) << 2;
  float creg[4] = {0.f, 0.f, 0.f, 0.f};
  float4 breg[4];
  if (L == 1) {
#pragma unroll
    for (int gg = 0; gg < 4; ++gg)
      breg[gg] = *reinterpret_cast<const float4*>(bias1 + gg * 512 + cbase + colq);
  }
  u32* myready = (L == 0) ? ready0 : ready1;

  for (int t = 0; t < 1024; ++t) {
    if (L == 0 && tid < 64) xidsl[tid] = xT[t * 128 + m0 + tid];
    if (tid == 0) {
      if (L == 0)
        wait3(t >= 1 ? &ready0[mh * 1024 + t - 1] : nullptr, 16u,
              t >= 8 ? &done0[mh * 1024 + t - 8] : nullptr, 32u, nullptr, 0u);
      else
        wait3(&ready0[mh * 1024 + t], 16u,
              t >= 1 ? &ready1[mh * 1024 + t - 1] : nullptr, 16u,
              t >= 8 ? &done1[mh * 1024 + t - 8] : nullptr, 18u);
    }
    __syncthreads();
    // ---- stage z into LDS via relaxed agent loads (MALL-coherent) ----
    if (L == 0) {
      const short* hsrc = t ? h0ring + (size_t)((t - 1) & 7) * 65536 : zslot;
      for (int i = tid; i < 4096; i += 512) {
        int r = i >> 6, seg = i & 63;
        const u64* sp = reinterpret_cast<const u64*>(hsrc + (size_t)(m0 + r) * 512) + seg * 2;
        u64 a = ld_h8(sp), b = ld_h8(sp + 1);
        ulonglong2 v; v.x = a; v.y = b;
        *reinterpret_cast<ulonglong2*>(smem + r * 1024 + ((seg * 16) ^ ((r & 7) << 4))) = v;
      }
      __syncthreads();
      if (tid == 0 && t >= 1) add_flag(&done0[mh * 1024 + t - 1]);
    } else {
      const short* s0 = h0ring + (size_t)(t & 7) * 65536;
      const short* s1 = t ? h1ring + (size_t)((t - 1) & 7) * 65536 : zslot;
      for (int i = tid; i < 8192; i += 512) {
        int r = i >> 7, seg = i & 127;
        const short* srow = (seg < 64) ? s0 + (size_t)(m0 + r) * 512 + seg * 8
                                       : s1 + (size_t)(m0 + r) * 512 + (seg - 64) * 8;
        const u64* sp = reinterpret_cast<const u64*>(srow);
        u64 a = ld_h8(sp), b = ld_h8(sp + 1);
        ulonglong2 v; v.x = a; v.y = b;
        *reinterpret_cast<ulonglong2*>(smem + r * 2048 + ((seg * 16) ^ ((r & 7) << 4))) = v;
      }
      __syncthreads();
      if (tid == 0) add_flag(&done0[mh * 1024 + t]);
      else if (tid == 64 && t >= 1) add_flag(&done1[mh * 1024 + t - 1]);
    }
    // ---- MFMA: [64 rows] x [128 gate-cols] ----
    f32x4 acc[2][2] = {};
    const char* ap = smem + (size_t)(mg + l15) * ROWB;
#pragma unroll 4
    for (int ks = 0; ks < NKS; ++ks) {
      int kb = ks * 64 + lq * 16;
      bf16x8 a0 = *reinterpret_cast<const bf16x8*>(ap + (kb ^ swz));
      bf16x8 a1 = *reinterpret_cast<const bf16x8*>(ap + 16 * ROWB + (kb ^ swz));
      bf16x8 b0 = *reinterpret_cast<const bf16x8*>(bbase + ks * 512);
      bf16x8 b1 = *reinterpret_cast<const bf16x8*>(bbase + NKS * 512 + ks * 512);
      acc[0][0] = __builtin_amdgcn_mfma_f32_16x16x32_bf16(a0, b0, acc[0][0], 0, 0, 0);
      acc[1][0] = __builtin_amdgcn_mfma_f32_16x16x32_bf16(a1, b0, acc[1][0], 0, 0, 0);
      acc[0][1] = __builtin_amdgcn_mfma_f32_16x16x32_bf16(a0, b1, acc[0][1], 0, 0, 0);
      acc[1][1] = __builtin_amdgcn_mfma_f32_16x16x32_bf16(a1, b1, acc[1][1], 0, 0, 0);
    }
    __syncthreads();
    // ---- gate exchange via LDS [4][64][32] f32, XOR-swizzled (2-way max) ----
    float* gl = reinterpret_cast<float*>(smem);
#pragma unroll
    for (int mf = 0; mf < 2; ++mf)
#pragma unroll
      for (int nfi = 0; nfi < 2; ++nfi)
#pragma unroll
        for (int r = 0; r < 4; ++r) {
          int lrow = mg + mf * 16 + lq * 4 + r;
          int lcol = (nfi * 16 + l15) ^ ((lrow & 7) << 2);
          gl[(g * 64 + lrow) * 32 + lcol] = acc[mf][nfi][r];
        }
    __syncthreads();
    // ---- elementwise: c in registers, packed 8B atomic h-store ----
    float4 Ai = *reinterpret_cast<const float4*>(&gl[(0 * 64 + row_e) * 32 + (colq ^ esw)]);
    float4 Af = *reinterpret_cast<const float4*>(&gl[(1 * 64 + row_e) * 32 + (colq ^ esw)]);
    float4 Ao = *reinterpret_cast<const float4*>(&gl[(2 * 64 + row_e) * 32 + (colq ^ esw)]);
    float4 Ag = *reinterpret_cast<const float4*>(&gl[(3 * 64 + row_e) * 32 + (colq ^ esw)]);
    float4 bi, bf_, bo, bg;
    if (L == 0) {
      const float* tb = table + (size_t)xidsl[row_e] * 2048 + cbase + colq;
      bi = *reinterpret_cast<const float4*>(tb);
      bf_ = *reinterpret_cast<const float4*>(tb + 512);
      bo = *reinterpret_cast<const float4*>(tb + 1024);
      bg = *reinterpret_cast<const float4*>(tb + 1536);
    } else {
      bi = breg[0]; bf_ = breg[1]; bo = breg[2]; bg = breg[3];
    }
    float hv[4];
    {
      float gi_[4] = {Ai.x + bi.x, Ai.y + bi.y, Ai.z + bi.z, Ai.w + bi.w};
      float gf_[4] = {Af.x + bf_.x, Af.y + bf_.y, Af.z + bf_.z, Af.w + bf_.w};
      float go_[4] = {Ao.x + bo.x, Ao.y + bo.y, Ao.z + bo.z, Ao.w + bo.w};
      float gg_[4] = {Ag.x + bg.x, Ag.y + bg.y, Ag.z + bg.z, Ag.w + bg.w};
#pragma unroll
      for (int j = 0; j < 4; ++j) {
        float cv = sigm(gf_[j]) * creg[j] + sigm(gi_[j]) * tanhf(gg_[j]);
        creg[j] = cv;
        hv[j] = sigm(go_[j]) * tanhf(cv);
      }
    }
    short* hdst = ((L == 0) ? h0ring : h1ring) + (size_t)(t & 7) * 65536;
    u64 pk = (u64)(unsigned short)f2bf(hv[0])
           | ((u64)(unsigned short)f2bf(hv[1]) << 16)
           | ((u64)(unsigned short)f2bf(hv[2]) << 32)
           | ((u64)(unsigned short)f2bf(hv[3]) << 48);
    st_h8(reinterpret_cast<u64*>(hdst + (size_t)(m0 + row_e) * 512 + cbase + colq), pk);
    vm_drain();
    __syncthreads();
    if (tid == 0) add_flag(&myready[mh * 1024 + t]);
  }
}

// ---------------- projection role (LN + [32x256] K=512 GEMM) ----------------
__device__ void proj_role(char* smem, int pid, int tid,
    const short* __restrict__ h1ring, u32* __restrict__ flags,
    const short* __restrict__ pWswz, const float* __restrict__ lng,
    const float* __restrict__ lnb, const float* __restrict__ pb,
    float* __restrict__ out)
{
  u32* ready1 = flags + 4096;
  u32* done1  = flags + 6144;
  const int mh = pid >> 1;
  const int prow0 = pid * 32;
  const int w = tid >> 6, lane = tid & 63, l15 = lane & 15, lq = lane >> 4;
  const int swz = (l15 & 7) << 4;
  const short* bp0 = pWswz + (size_t)(w * 2) * 8192 + lane * 8;
  const short* bp1 = bp0 + 8192;

  for (int t = 0; t < 1024; ++t) {
    if (tid == 0) wait3(&ready1[mh * 1024 + t], 16u, nullptr, 0u, nullptr, 0u);
    __syncthreads();
    const short* h1p = h1ring + (size_t)(t & 7) * 65536;
    for (int i = tid; i < 2048; i += 512) {
      int r = i >> 6, seg = i & 63;
      const u64* sp = reinterpret_cast<const u64*>(h1p + (size_t)(prow0 + r) * 512) + seg * 2;
      u64 a = ld_h8(sp), b = ld_h8(sp + 1);
      ulonglong2 v; v.x = a; v.y = b;
      *reinterpret_cast<ulonglong2*>(smem + r * 1024 + seg * 16) = v;
    }
    __syncthreads();
    if (tid == 0) add_flag(&done1[mh * 1024 + t]);
    {
      // LayerNorm: 16 threads/row, stride-16 interleaved (conflict-free pairs)
      int row = tid >> 4, j = tid & 15;
      const short* hr = reinterpret_cast<const short*>(smem) + row * 512;
      float s1 = 0.f, s2 = 0.f;
#pragma unroll
      for (int kk = 0; kk < 32; ++kk) {
        float v = bf2f(hr[kk * 16 + j]);
        s1 += v; s2 += v * v;
      }
#pragma unroll
      for (int d = 1; d < 16; d <<= 1) { s1 += __shfl_xor(s1, d, 64); s2 += __shfl_xor(s2, d, 64); }
      float mu = s1 * (1.f / 512.f);
      float rs = rsqrtf(s2 * (1.f / 512.f) - mu * mu + 1e-5f);
      char* zn = smem + 32768;
#pragma unroll
      for (int kk = 0; kk < 32; ++kk) {
        int k = kk * 16 + j;
        float v = bf2f(hr[k]);
        float nv = (v - mu) * rs * lng[k] + lnb[k];
        *reinterpret_cast<short*>(zn + row * 1024 + ((k * 2) ^ ((row & 7) << 4))) = f2bf(nv);
      }
    }
    __syncthreads();
    const char* ap = smem + 32768 + l15 * 1024;
    f32x4 acc[2][2] = {};
#pragma unroll 4
    for (int ks = 0; ks < 16; ++ks) {
      int kb = ks * 64 + lq * 16;
      bf16x8 a0 = *reinterpret_cast<const bf16x8*>(ap + (kb ^ swz));
      bf16x8 a1 = *reinterpret_cast<const bf16x8*>(ap + 16 * 1024 + (kb ^ swz));
      bf16x8 bv0 = *reinterpret_cast<const bf16x8*>(bp0 + ks * 512);
      bf16x8 bv1 = *reinterpret_cast<const bf16x8*>(bp1 + ks * 512);
      acc[0][0] = __builtin_amdgcn_mfma_f32_16x16x32_bf16(a0, bv0, acc[0][0], 0, 0, 0);
      acc[1][0] = __builtin_amdgcn_mfma_f32_16x16x32_bf16(a1, bv0, acc[1][0], 0, 0, 0);
      acc[0][1] = __builtin_amdgcn_mfma_f32_16x16x32_bf16(a0, bv1, acc[0][1], 0, 0, 0);
      acc[1][1] = __builtin_amdgcn_mfma_f32_16x16x32_bf16(a1, bv1, acc[1][1], 0, 0, 0);
    }
#pragma unroll
    for (int mf = 0; mf < 2; ++mf)
#pragma unroll
      for (int nfi = 0; nfi < 2; ++nfi)
#pragma unroll
        for (int r = 0; r < 4; ++r) {
          int vcol = (w * 2 + nfi) * 16 + l15;
          int rowg = prow0 + mf * 16 + lq * 4 + r;
          out[(size_t)rowg * 262144 + (size_t)t * 256 + vcol] = acc[mf][nfi][r] + pb[vcol];
        }
    __syncthreads();
  }
}

__global__ __launch_bounds__(512) void persist_kernel(
    const short* __restrict__ W0h, const short* __restrict__ W1,
    const float* __restrict__ table, const float* __restrict__ bias1,
    const int* __restrict__ xT, short* __restrict__ h0ring, short* __restrict__ h1ring,
    const short* __restrict__ zslot, u32* __restrict__ flags,
    const short* __restrict__ pWswz, const float* __restrict__ lng,
    const float* __restrict__ lnb, const float* __restrict__ pb, float* __restrict__ out)
{
  __shared__ __align__(16) char smem[131328];
  const int wg = blockIdx.x, tid = threadIdx.x;
  if (wg < 32)
    lstm_role<0>(smem, wg, tid, W0h, table, nullptr, xT, h0ring, h1ring, zslot, flags);
  else if (wg < 64)
    lstm_role<1>(smem, wg - 32, tid, W1, nullptr, bias1, xT, h0ring, h1ring, zslot, flags);
  else
    proj_role(smem, wg - 64, tid, h1ring, flags, pWswz, lng, lnb, pb, out);
}

extern "C" void kernel_launch(void* const* d_in, const int* in_sizes, int n_in,
                              void* d_out, int out_size, void* d_ws, size_t ws_size,
                              hipStream_t stream) {
  const int*   x    = (const int*)d_in[0];
  const float* emb  = (const float*)d_in[1];
  const float* W    = (const float*)d_in[2];
  const float* bias = (const float*)d_in[3];
  const float* lng  = (const float*)d_in[4];
  const float* lnb  = (const float*)d_in[5];
  const float* pW   = (const float*)d_in[6];
  const float* pb   = (const float*)d_in[7];
  float* out = (float*)d_out;

  char* ws = (char*)d_ws;
  short* W0h   = (short*)(ws + 0);          // 2 MB
  short* W1sw  = (short*)(ws + 2097152);    // 4 MB
  short* W0x   = (short*)(ws + 6291456);    // 2 MB
  short* pWsw  = (short*)(ws + 8388608);    // 256 KB
  float* table = (float*)(ws + 8650752);    // 2 MB
  int*   xT    = (int*)(ws + 10747904);     // 512 KB
  short* h0ring= (short*)(ws + 11272192);   // 1 MB
  short* h1ring= (short*)(ws + 12320768);   // 1 MB
  short* zslot = (short*)(ws + 13369344);   // 128 KB
  u32*   flags = (u32*)(ws + 13500416);     // 32 KB

  hipMemsetAsync(ws + 13369344, 0, 131072 + 32768, stream);
  swz_generic<<<dim3(512), dim3(256), 0, stream>>>(W, W0h, 1024, 512, 16, 131072);
  swz_generic<<<dim3(1024), dim3(256), 0, stream>>>(W + 2048 * 1024, W1sw, 1024, 0, 32, 262144);
  swz_generic<<<dim3(512), dim3(256), 0, stream>>>(W, W0x, 1024, 0, 16, 131072);
  swz_generic<<<dim3(64), dim3(256), 0, stream>>>(pW, pWsw, 512, 0, 16, 16384);
  xpose_kernel<<<dim3(512), dim3(256), 0, stream>>>(x, xT);
  table_kernel<<<dim3(4, 16), dim3(512), 0, stream>>>(emb, W0x, bias, table);

  persist_kernel<<<dim3(68), dim3(512), 0, stream>>>(
      W0h, W1sw, table, bias + 2048, xT, h0ring, h1ring, zslot, flags,
      pWsw, lng, lnb, pb, out);
}